// Round 4
// baseline (164.309 us; speedup 1.0000x reference)
//
#include <hip/hip_runtime.h>
#include <hip/hip_bf16.h>
#include <stdint.h>

typedef __attribute__((ext_vector_type(8))) short short8;
typedef __attribute__((ext_vector_type(4))) float f32x4;

// Problem constants
#define BATCH 4
#define SEQ   2048
#define EMB   1024
#define HEADS 16
#define DHEAD 64
#define MROWS (BATCH * SEQ)   // 8192

// exp(s/8) == exp2(s * 0.125*log2(e)); fold into Q at bf16-pack time
#define QSCALE 0.18033688011112042f

__device__ inline unsigned short f2bf(float f) {
    unsigned int u = __float_as_uint(f);
    unsigned int r = (u + 0x7fffu + ((u >> 16) & 1u)) >> 16;
    return (unsigned short)r;
}

__device__ __forceinline__ void gl_lds16(const short* g, short* l) {
    __builtin_amdgcn_global_load_lds(
        (const __attribute__((address_space(1))) void*)g,
        (__attribute__((address_space(3))) void*)l, 16, 0, 0);
}

// ---------------- fused pack x -> bf16 + f32 passthrough ----------------
__global__ __launch_bounds__(256) void pack_x(const float* __restrict__ src,
                                              unsigned short* __restrict__ dst,
                                              float* __restrict__ pass) {
    int i = (blockIdx.x * 256 + threadIdx.x) * 8;
    const float4* s = reinterpret_cast<const float4*>(src + i);
    float4 f0 = s[0];
    float4 f1 = s[1];
    union { unsigned short u[8]; short8 v; } o;
    o.u[0] = f2bf(f0.x); o.u[1] = f2bf(f0.y); o.u[2] = f2bf(f0.z); o.u[3] = f2bf(f0.w);
    o.u[4] = f2bf(f1.x); o.u[5] = f2bf(f1.y); o.u[6] = f2bf(f1.z); o.u[7] = f2bf(f1.w);
    *reinterpret_cast<short8*>(dst + i) = o.v;
    float4* p = reinterpret_cast<float4*>(pass + i);
    p[0] = f0;
    p[1] = f1;
}

// ---------------- pack 3 weights -> bf16, one dispatch ----------------
__global__ __launch_bounds__(256) void pack_w3(const float* __restrict__ wq,
                                               const float* __restrict__ wk,
                                               const float* __restrict__ wv,
                                               unsigned short* __restrict__ dq,
                                               unsigned short* __restrict__ dk,
                                               unsigned short* __restrict__ dv) {
    const float* src = blockIdx.y == 0 ? wq : blockIdx.y == 1 ? wk : wv;
    unsigned short* dst = blockIdx.y == 0 ? dq : blockIdx.y == 1 ? dk : dv;
    int i = (blockIdx.x * 256 + threadIdx.x) * 8;
    const float4* s = reinterpret_cast<const float4*>(src + i);
    float4 f0 = s[0];
    float4 f1 = s[1];
    union { unsigned short u[8]; short8 v; } o;
    o.u[0] = f2bf(f0.x); o.u[1] = f2bf(f0.y); o.u[2] = f2bf(f0.z); o.u[3] = f2bf(f0.w);
    o.u[4] = f2bf(f1.x); o.u[5] = f2bf(f1.y); o.u[6] = f2bf(f1.z); o.u[7] = f2bf(f1.w);
    *reinterpret_cast<short8*>(dst + i) = o.v;
}

// ---------------- GEMM (m97 structure): C[m,e] = sum_k A[m,k]*B[e,k] ----
// MODE 0: fused QK — grid.y spans 2048 cols = [Wq | Wk]; store bf16
//         head-major [2*64][SEQ][64] (Qh then Kh), Q scaled by QSCALE.
// MODE 1: V — store f32 to out, scaled by diag.
template <int MODE>
__global__ __launch_bounds__(256) void gemm_bt(const short* __restrict__ A,
                                               const short* __restrict__ Bm,
                                               unsigned short* __restrict__ Cb,
                                               float* __restrict__ out,
                                               const float* __restrict__ dgp) {
    constexpr int K = EMB;
    __shared__ short As[128 * 32];   // linear: global_load_lds needs lane-contiguous dest
    __shared__ short Bs[128 * 32];
    const int m0 = blockIdx.x * 128;
    const int n0 = blockIdx.y * 128;
    const int t = threadIdx.x;
    const int lane = t & 63;
    const int w = t >> 6;                // 4 waves
    const int wr = w >> 1, wc = w & 1;   // 2x2 wave grid, 64x64 per wave

    f32x4 acc[4][4] = {};

    const short* gA = A + (size_t)(m0 + (t >> 2)) * K + (t & 3) * 8;
    const short* gB = Bm + (size_t)(n0 + (t >> 2)) * K + (t & 3) * 8;
    short* lA0 = As + w * 512;           // wave-uniform LDS bases
    short* lA1 = As + 2048 + w * 512;
    short* lB0 = Bs + w * 512;
    short* lB1 = Bs + 2048 + w * 512;

    const int kq = (lane >> 4) * 8;
    const int fr = lane & 15;

    for (int k0 = 0; k0 < K; k0 += 32) {
        gl_lds16(gA + k0, lA0);
        gl_lds16(gA + 64 * K + k0, lA1);
        gl_lds16(gB + k0, lB0);
        gl_lds16(gB + 64 * K + k0, lB1);
        __syncthreads();

        short8 a[4], b[4];
#pragma unroll
        for (int i = 0; i < 4; i++)
            a[i] = *(const short8*)&As[(wr * 64 + i * 16 + fr) * 32 + kq];
#pragma unroll
        for (int j = 0; j < 4; j++)
            b[j] = *(const short8*)&Bs[(wc * 64 + j * 16 + fr) * 32 + kq];
#pragma unroll
        for (int i = 0; i < 4; i++)
#pragma unroll
            for (int j = 0; j < 4; j++)
                acc[i][j] = __builtin_amdgcn_mfma_f32_16x16x32_bf16(a[i], b[j], acc[i][j], 0, 0, 0);
        __syncthreads();
    }

    // epilogue: C layout col = lane&15, row = 4*(lane>>4)+r
    const int gr_base = m0 + wr * 64 + (lane >> 4) * 4;
    const int gc_base = n0 + wc * 64 + fr;
#pragma unroll
    for (int i = 0; i < 4; i++) {
#pragma unroll
        for (int j = 0; j < 4; j++) {
            const int col = gc_base + j * 16;
#pragma unroll
            for (int r = 0; r < 4; r++) {
                const int grow = gr_base + i * 16 + r;
                const int bb = grow >> 11;
                const int nn = grow & 2047;
                if (MODE == 0) {
                    const int sel = col >> 10;       // 0 = Q, 1 = K
                    const int cc = col & 1023;
                    const int hh = cc >> 6;
                    const int dd = cc & 63;
                    const float sc = sel ? 1.0f : QSCALE;
                    Cb[(((size_t)((sel << 6) + (bb << 4) + hh) * SEQ + nn) << 6) + dd] =
                        f2bf(acc[i][j][r] * sc);
                } else {
                    const int hh = col >> 6;
                    const float d = dgp[((bb << 4) + hh) * SEQ + nn];
                    out[(size_t)grow * EMB + col] = acc[i][j][r] * d;
                }
            }
        }
    }
}

// ---------------- diag kernel v4 ----------------------------------------
// Qh/Kh head-major [64][2048][64] bf16 (Q pre-scaled).
// Block = (bh, 256-q-row tile), 256 threads = 4 waves x 64 q-rows each.
// Per sub: one b0/b1 LDS read pair shared by 4 q-tiles (8 MFMA) ->
// 2 B LDS traffic per score. Diag numerators grabbed in a pre-pass from
// global; hot loop has no compares.
#define KT 128

__global__ __launch_bounds__(256) void diag_kernel(const short* __restrict__ Qh,
                                                   const short* __restrict__ Kh,
                                                   float* __restrict__ dgp) {
    const int bh = blockIdx.x >> 3;     // 0..63
    const int qt = blockIdx.x & 7;      // 8 q-tiles of 256 rows
    __shared__ short Ks[2][KT][64];

    const int t = threadIdx.x;
    const int lane = t & 63;
    const int w = t >> 6;               // 0..3
    const int rl = lane & 15;
    const int g = lane >> 4;            // 0..3
    const int kq = g * 8;

    const short* Kbh = Kh + (size_t)bh * SEQ * DHEAD;
    const short* Qbh = Qh + (size_t)bh * SEQ * DHEAD;

    // Q fragments: 4 tiles of 16 rows (64 q-rows per wave)
    const int qbase = qt * 256 + w * 64;
    short8 a0[4], a1[4];
#pragma unroll
    for (int i = 0; i < 4; i++) {
        const int qrow = qbase + i * 16 + rl;
        a0[i] = *(const short8*)(Qbh + qrow * DHEAD + kq);
        a1[i] = *(const short8*)(Qbh + qrow * DHEAD + kq + 32);
    }

    // diag numerator pre-pass: K rows == Q rows for each tile
    float sdiag[4];
    const int rr = rl - g * 4;          // valid lane iff 0 <= rr < 4
#pragma unroll
    for (int i = 0; i < 4; i++) {
        const int krow = qbase + i * 16 + rl;
        const short8 b0d = *(const short8*)(Kbh + krow * DHEAD + kq);
        const short8 b1d = *(const short8*)(Kbh + krow * DHEAD + kq + 32);
        f32x4 cd = {};
        cd = __builtin_amdgcn_mfma_f32_16x16x32_bf16(a0[i], b0d, cd, 0, 0, 0);
        cd = __builtin_amdgcn_mfma_f32_16x16x32_bf16(a1[i], b1d, cd, 0, 0, 0);
        sdiag[i] = (rr >= 0 && rr < 4) ? cd[rr] : 0.f;
    }

    // staging map: 256 threads cover 128 rows x 8 16B-blocks, 4 blocks each
    const int sr = t >> 1;              // 0..127
    const int sh = (t & 1) * 4;         // 0 or 4

    // stage tile 0 (XOR-swizzled: block ^= row&7)
#pragma unroll
    for (int j = 0; j < 4; j++) {
        const int cb = sh + j;
        const int cs = (cb ^ (sr & 7)) * 8;
        *(short8*)&Ks[0][sr][cs] = *(const short8*)&Kbh[sr * DHEAD + cb * 8];
    }
    __syncthreads();

    // swizzled read blocks (row&7 == rl&7 == lane&7 since rows step by 16)
    const int blk0 = (g ^ (lane & 7)) * 8;
    const int blk1 = ((g + 4) ^ (lane & 7)) * 8;

    float ssum[4][4] = {};
    int buf = 0;

    for (int kt = 0; kt < SEQ / KT; ++kt) {
        short8 p[4];
        if (kt < SEQ / KT - 1) {
            const short* src = Kbh + (kt + 1) * KT * DHEAD;
#pragma unroll
            for (int j = 0; j < 4; j++)
                p[j] = *(const short8*)&src[sr * DHEAD + (sh + j) * 8];
        }
#pragma unroll
        for (int sub = 0; sub < 8; ++sub) {
            const int row = sub * 16 + rl;
            const short8 b0 = *(const short8*)&Ks[buf][row][blk0];
            const short8 b1 = *(const short8*)&Ks[buf][row][blk1];
            f32x4 c[4];
#pragma unroll
            for (int i = 0; i < 4; i++) {
                c[i] = __builtin_amdgcn_mfma_f32_16x16x32_bf16(a0[i], b0, f32x4{}, 0, 0, 0);
                c[i] = __builtin_amdgcn_mfma_f32_16x16x32_bf16(a1[i], b1, c[i], 0, 0, 0);
            }
#pragma unroll
            for (int i = 0; i < 4; i++)
#pragma unroll
                for (int r = 0; r < 4; ++r)
                    ssum[i][r] += __builtin_amdgcn_exp2f(c[i][r]);
        }
        if (kt < SEQ / KT - 1) {
            __syncthreads();
#pragma unroll
            for (int j = 0; j < 4; j++) {
                const int cb = sh + j;
                const int cs = (cb ^ (sr & 7)) * 8;
                *(short8*)&Ks[buf ^ 1][sr][cs] = p[j];
            }
            __syncthreads();
        }
        buf ^= 1;
    }

    // reduce partial sums across the 16-lane column groups
#pragma unroll
    for (int i = 0; i < 4; i++)
#pragma unroll
        for (int r = 0; r < 4; r++) {
            float v = ssum[i][r];
            v += __shfl_xor(v, 1);
            v += __shfl_xor(v, 2);
            v += __shfl_xor(v, 4);
            v += __shfl_xor(v, 8);
            ssum[i][r] = v;
        }

    if (rr >= 0 && rr < 4) {
#pragma unroll
        for (int i = 0; i < 4; i++) {
            const float dg = __builtin_amdgcn_exp2f(sdiag[i]) / ssum[i][rr];
            dgp[bh * SEQ + qbase + i * 16 + rl] = dg;
        }
    }
}

extern "C" void kernel_launch(void* const* d_in, const int* in_sizes, int n_in,
                              void* d_out, int out_size, void* d_ws, size_t ws_size,
                              hipStream_t stream) {
    const float* x  = (const float*)d_in[0];
    const float* Wq = (const float*)d_in[1];
    const float* Wk = (const float*)d_in[2];
    const float* Wv = (const float*)d_in[3];
    float* out = (float*)d_out;
    char* ws = (char*)d_ws;

    const size_t xb_off  = 0;
    const size_t wq_off  = xb_off + (size_t)MROWS * EMB * 2;
    const size_t wk_off  = wq_off + (size_t)EMB * EMB * 2;   // contiguous after wq
    const size_t wv_off  = wk_off + (size_t)EMB * EMB * 2;
    const size_t q_off   = wv_off + (size_t)EMB * EMB * 2;
    const size_t k_off   = q_off + (size_t)MROWS * EMB * 2;  // contiguous after q
    const size_t dg_off  = k_off + (size_t)MROWS * EMB * 2;

    short* xb  = (short*)(ws + xb_off);
    short* wqb = (short*)(ws + wq_off);
    short* wkb = (short*)(ws + wk_off);
    short* wvb = (short*)(ws + wv_off);
    short* Qh  = (short*)(ws + q_off);
    short* Kh  = (short*)(ws + k_off);
    float* dgp = (float*)(ws + dg_off);

    const int nx = MROWS * EMB;    // 8388608
    const int nw = EMB * EMB;      // 1048576

    pack_x<<<nx / 2048, 256, 0, stream>>>(x, (unsigned short*)xb,
                                          out + (size_t)MROWS * EMB);
    pack_w3<<<dim3(nw / 2048, 3), 256, 0, stream>>>(Wq, Wk, Wv,
                                                    (unsigned short*)wqb,
                                                    (unsigned short*)wkb,
                                                    (unsigned short*)wvb);

    // fused Q+K projection: B = [Wq | Wk] (contiguous), N = 2048
    gemm_bt<0><<<dim3(MROWS / 128, 2048 / 128), 256, 0, stream>>>(
        xb, wqb, (unsigned short*)Qh, nullptr, nullptr);

    diag_kernel<<<BATCH * HEADS * (SEQ / 256), 256, 0, stream>>>(Qh, Kh, dgp);

    gemm_bt<1><<<dim3(MROWS / 128, EMB / 128), 256, 0, stream>>>(
        xb, wvb, nullptr, out, dgp);
}